// Round 5
// baseline (142.519 us; speedup 1.0000x reference)
//
#include <hip/hip_runtime.h>

namespace {
constexpr int N_ELEMS  = 262144;
constexpr int N_NODES  = 263169;
constexpr int N_WORK   = N_ELEMS * 4;     // (element, ip) units
constexpr int BLK      = 256;
constexpr size_t WS_NEEDED = size_t(N_ELEMS) * 12 * sizeof(float);

// folded material constants (fp32, match reference math)
constexpr float GC_2L0  = 0.09f;                 // G_C / (2*L_0)
constexpr float L0SQ    = 0.015f * 0.015f;
constexpr float MU_     = 80.76923076923077f;    // E/(2(1+nu))
constexpr float K_MOD   = 175.0f;                // lam + 2mu/3 (exact)
constexpr float PENALTY = 1799.82f;              // G_C/L_0*(1/PF_TOL^2-1)
}

typedef float vfloat4 __attribute__((ext_vector_type(4)));
typedef int   vint4   __attribute__((ext_vector_type(4)));

__device__ __forceinline__ float waveReduce(float x) {
#pragma unroll
    for (int off = 32; off; off >>= 1) x += __shfl_down(x, off, 64);
    return x;
}

// ---------------------------------------------------------------------------
// Kernel 1: gather nodal fields into packed per-element workspace.
// All divergent traffic lives here; c/u/v (~3 MB) are L2-resident.
// Also computes the nodal irreversibility penalty.
// ---------------------------------------------------------------------------
__global__ __launch_bounds__(256) void gather_pack(
    const float* __restrict__ u, const float* __restrict__ v,
    const float* __restrict__ c, const float* __restrict__ prev_c,
    const int* __restrict__ conn,
    float* __restrict__ ws, float* __restrict__ out)
{
    const int tid = blockIdx.x * blockDim.x + threadIdx.x;

    if (tid < N_ELEMS) {
        const vint4 cn = *reinterpret_cast<const vint4*>(conn + 4ll * tid);
        vfloat4 cv, uv0, uv1;
        cv.x = c[cn.x]; cv.y = c[cn.y]; cv.z = c[cn.z]; cv.w = c[cn.w];
        uv0.x = u[cn.x]; uv0.y = v[cn.x]; uv0.z = u[cn.y]; uv0.w = v[cn.y];
        uv1.x = u[cn.z]; uv1.y = v[cn.z]; uv1.z = u[cn.w]; uv1.w = v[cn.w];
        vfloat4* wp = reinterpret_cast<vfloat4*>(ws) + 3ll * tid;
        wp[0] = cv; wp[1] = uv0; wp[2] = uv1;
    }

    float Eirr = 0.f;
    if (tid < N_NODES) {
        float d = fmaxf(prev_c[tid] - c[tid], 0.f);
        Eirr = 0.5f * PENALTY * d * d;
    }
    Eirr = waveReduce(Eirr);
    __shared__ float sI[4];
    const int lane = threadIdx.x & 63, wid = threadIdx.x >> 6;
    if (lane == 0) sI[wid] = Eirr;
    __syncthreads();
    if (threadIdx.x == 0)
        atomicAdd(&out[2], sI[0] + sI[1] + sI[2] + sI[3]);
}

// ---------------------------------------------------------------------------
// Kernel 2: pure streaming energy — zero indirection, fully dense loads.
// One thread per (element, ip). Sibling lanes (same element) broadcast-read
// the 48B packed ws record from L1.
// ---------------------------------------------------------------------------
__global__ __launch_bounds__(256) void stream_energy(
    const float* __restrict__ ws,
    const float* __restrict__ Nf, const float* __restrict__ dNdx,
    const float* __restrict__ B, const float* __restrict__ vol,
    float* __restrict__ out)
{
    const int unit = blockIdx.x * blockDim.x + threadIdx.x;  // < N_WORK exactly
    const int e = unit >> 2, ip = unit & 3;

    const vfloat4* wp = reinterpret_cast<const vfloat4*>(ws) + 3ll * e;
    const vfloat4 cv  = wp[0];
    const vfloat4 uva = wp[1];   // u0 v0 u1 v1
    const vfloat4 uvb = wp[2];   // u2 v2 u3 v3

    const vfloat4 Nr = *reinterpret_cast<const vfloat4*>(Nf + 16ll * e + 4 * ip);

    const float* Dp = dNdx + 32ll * e + 8 * ip;
    const vfloat4 dx = *reinterpret_cast<const vfloat4*>(Dp);
    const vfloat4 dy = *reinterpret_cast<const vfloat4*>(Dp + 4);

    const float* Bp = B + 96ll * e + 24 * ip;
    const vfloat4 b0 = *reinterpret_cast<const vfloat4*>(Bp +  0);
    const vfloat4 b1 = *reinterpret_cast<const vfloat4*>(Bp +  4);
    const vfloat4 b2 = *reinterpret_cast<const vfloat4*>(Bp +  8);
    const vfloat4 b3 = *reinterpret_cast<const vfloat4*>(Bp + 12);
    const vfloat4 b4 = *reinterpret_cast<const vfloat4*>(Bp + 16);
    const vfloat4 b5 = *reinterpret_cast<const vfloat4*>(Bp + 20);

    const float vip = vol[unit];

    // fracture / degradation
    const float o0 = 1.f - cv.x, o1 = 1.f - cv.y, o2 = 1.f - cv.z, o3 = 1.f - cv.w;
    const float omc = Nr.x * o0 + Nr.y * o1 + Nr.z * o2 + Nr.w * o3;
    const float g   = omc * omc;
    const float cip = 1.f - omc;
    const float gx  = dx.x * cv.x + dx.y * cv.y + dx.z * cv.z + dx.w * cv.w;
    const float gy  = dy.x * cv.x + dy.y * cv.y + dy.z * cv.z + dy.w * cv.w;
    float Efr = GC_2L0 * (cip * cip + L0SQ * (gx * gx + gy * gy)) * vip;

    // strain energy
    const float exx = b0.x * uva.x + b0.y * uva.y + b0.z * uva.z + b0.w * uva.w
                    + b1.x * uvb.x + b1.y * uvb.y + b1.z * uvb.z + b1.w * uvb.w;
    const float eyy = b2.x * uva.x + b2.y * uva.y + b2.z * uva.z + b2.w * uva.w
                    + b3.x * uvb.x + b3.y * uvb.y + b3.z * uvb.z + b3.w * uvb.w;
    const float gxy = b4.x * uva.x + b4.y * uva.y + b4.z * uva.z + b4.w * uva.w
                    + b5.x * uvb.x + b5.y * uvb.y + b5.z * uvb.z + b5.w * uvb.w;
    const float exy = 0.5f * gxy;
    const float tr  = exx + eyy, tr3 = tr * (1.f / 3.f);
    const float dxx = exx - tr3, dyy = eyy - tr3, dzz = -tr3;
    const float dev2 = dxx * dxx + dyy * dyy + dzz * dzz + 2.f * exy * exy;
    const float trp = fmaxf(tr, 0.f), trn = fminf(tr, 0.f);
    float Eel = ((0.5f * K_MOD * trp * trp + MU_ * dev2) * g
                 + 0.5f * K_MOD * trn * trn) * vip;

    Eel = waveReduce(Eel);
    Efr = waveReduce(Efr);
    __shared__ float sE[4], sF[4];
    const int lane = threadIdx.x & 63, wid = threadIdx.x >> 6;
    if (lane == 0) { sE[wid] = Eel; sF[wid] = Efr; }
    __syncthreads();
    if (threadIdx.x == 0) {
        atomicAdd(&out[0], sE[0] + sE[1] + sE[2] + sE[3]);
        atomicAdd(&out[1], sF[0] + sF[1] + sF[2] + sF[3]);
    }
}

// ---------------------------------------------------------------------------
// Fallback (round-4 fused kernel) in case ws_size < 12.6 MB.
// ---------------------------------------------------------------------------
__global__ __launch_bounds__(256) void fused_energy(
    const float* __restrict__ u, const float* __restrict__ v,
    const float* __restrict__ c, const float* __restrict__ prev_c,
    const int* __restrict__ conn,
    const float* __restrict__ Nf, const float* __restrict__ dNdx,
    const float* __restrict__ B, const float* __restrict__ vol,
    float* __restrict__ out)
{
    const int tid = blockIdx.x * blockDim.x + threadIdx.x;
    const int NT = N_WORK / 2;
    const int u0 = tid, u1 = tid + NT;
    const int e0 = u0 >> 2, ip0 = u0 & 3;
    const int e1 = u1 >> 2, ip1 = u1 & 3;

    const vint4 cn0 = *reinterpret_cast<const vint4*>(conn + 4ll * e0);
    const vint4 cn1 = *reinterpret_cast<const vint4*>(conn + 4ll * e1);

    const vfloat4 Nr0 = *reinterpret_cast<const vfloat4*>(Nf + 16ll * e0 + 4 * ip0);
    const vfloat4 Nr1 = *reinterpret_cast<const vfloat4*>(Nf + 16ll * e1 + 4 * ip1);
    const float* Dp0 = dNdx + 32ll * e0 + 8 * ip0;
    const float* Dp1 = dNdx + 32ll * e1 + 8 * ip1;
    const vfloat4 dxa = *reinterpret_cast<const vfloat4*>(Dp0);
    const vfloat4 dya = *reinterpret_cast<const vfloat4*>(Dp0 + 4);
    const vfloat4 dxb = *reinterpret_cast<const vfloat4*>(Dp1);
    const vfloat4 dyb = *reinterpret_cast<const vfloat4*>(Dp1 + 4);
    const float* Bp0 = B + 96ll * e0 + 24 * ip0;
    const float* Bp1 = B + 96ll * e1 + 24 * ip1;
    const vfloat4 a0 = *reinterpret_cast<const vfloat4*>(Bp0 +  0);
    const vfloat4 a1 = *reinterpret_cast<const vfloat4*>(Bp0 +  4);
    const vfloat4 a2 = *reinterpret_cast<const vfloat4*>(Bp0 +  8);
    const vfloat4 a3 = *reinterpret_cast<const vfloat4*>(Bp0 + 12);
    const vfloat4 a4 = *reinterpret_cast<const vfloat4*>(Bp0 + 16);
    const vfloat4 a5 = *reinterpret_cast<const vfloat4*>(Bp0 + 20);
    const vfloat4 b0 = *reinterpret_cast<const vfloat4*>(Bp1 +  0);
    const vfloat4 b1 = *reinterpret_cast<const vfloat4*>(Bp1 +  4);
    const vfloat4 b2 = *reinterpret_cast<const vfloat4*>(Bp1 +  8);
    const vfloat4 b3 = *reinterpret_cast<const vfloat4*>(Bp1 + 12);
    const vfloat4 b4 = *reinterpret_cast<const vfloat4*>(Bp1 + 16);
    const vfloat4 b5 = *reinterpret_cast<const vfloat4*>(Bp1 + 20);
    const float vipa = vol[4ll * e0 + ip0];
    const float vipb = vol[4ll * e1 + ip1];

    float Eirr = 0.f;
    if (tid < N_NODES) {
        float d = fmaxf(prev_c[tid] - c[tid], 0.f);
        Eirr = 0.5f * PENALTY * d * d;
    }

    const float ca0 = c[cn0.x], ca1 = c[cn0.y], ca2 = c[cn0.z], ca3 = c[cn0.w];
    const float cb0 = c[cn1.x], cb1 = c[cn1.y], cb2 = c[cn1.z], cb3 = c[cn1.w];
    const float ua0 = u[cn0.x], va0 = v[cn0.x];
    const float ua1 = u[cn0.y], va1 = v[cn0.y];
    const float ua2 = u[cn0.z], va2 = v[cn0.z];
    const float ua3 = u[cn0.w], va3 = v[cn0.w];
    const float ub0 = u[cn1.x], vb0 = v[cn1.x];
    const float ub1 = u[cn1.y], vb1 = v[cn1.y];
    const float ub2 = u[cn1.z], vb2 = v[cn1.z];
    const float ub3 = u[cn1.w], vb3 = v[cn1.w];

    float Eel = 0.f, Efr = 0.f;
    {
        const float o0 = 1.f - ca0, o1 = 1.f - ca1, o2 = 1.f - ca2, o3 = 1.f - ca3;
        const float omc = Nr0.x * o0 + Nr0.y * o1 + Nr0.z * o2 + Nr0.w * o3;
        const float g = omc * omc, cip = 1.f - omc;
        const float gx = dxa.x * ca0 + dxa.y * ca1 + dxa.z * ca2 + dxa.w * ca3;
        const float gy = dya.x * ca0 + dya.y * ca1 + dya.z * ca2 + dya.w * ca3;
        Efr += GC_2L0 * (cip * cip + L0SQ * (gx * gx + gy * gy)) * vipa;
        const float exx = a0.x * ua0 + a0.y * va0 + a0.z * ua1 + a0.w * va1
                        + a1.x * ua2 + a1.y * va2 + a1.z * ua3 + a1.w * va3;
        const float eyy = a2.x * ua0 + a2.y * va0 + a2.z * ua1 + a2.w * va1
                        + a3.x * ua2 + a3.y * va2 + a3.z * ua3 + a3.w * va3;
        const float gxy = a4.x * ua0 + a4.y * va0 + a4.z * ua1 + a4.w * va1
                        + a5.x * ua2 + a5.y * va2 + a5.z * ua3 + a5.w * va3;
        const float exy = 0.5f * gxy;
        const float tr = exx + eyy, tr3 = tr * (1.f / 3.f);
        const float dxx = exx - tr3, dyy = eyy - tr3, dzz = -tr3;
        const float dev2 = dxx * dxx + dyy * dyy + dzz * dzz + 2.f * exy * exy;
        const float trp = fmaxf(tr, 0.f), trn = fminf(tr, 0.f);
        Eel += ((0.5f * K_MOD * trp * trp + MU_ * dev2) * g
                + 0.5f * K_MOD * trn * trn) * vipa;
    }
    {
        const float o0 = 1.f - cb0, o1 = 1.f - cb1, o2 = 1.f - cb2, o3 = 1.f - cb3;
        const float omc = Nr1.x * o0 + Nr1.y * o1 + Nr1.z * o2 + Nr1.w * o3;
        const float g = omc * omc, cip = 1.f - omc;
        const float gx = dxb.x * cb0 + dxb.y * cb1 + dxb.z * cb2 + dxb.w * cb3;
        const float gy = dyb.x * cb0 + dyb.y * cb1 + dyb.z * cb2 + dyb.w * cb3;
        Efr += GC_2L0 * (cip * cip + L0SQ * (gx * gx + gy * gy)) * vipb;
        const float exx = b0.x * ub0 + b0.y * vb0 + b0.z * ub1 + b0.w * vb1
                        + b1.x * ub2 + b1.y * vb2 + b1.z * ub3 + b1.w * vb3;
        const float eyy = b2.x * ub0 + b2.y * vb0 + b2.z * ub1 + b2.w * vb1
                        + b3.x * ub2 + b3.y * vb2 + b3.z * ub3 + b3.w * vb3;
        const float gxy = b4.x * ub0 + b4.y * vb0 + b4.z * ub1 + b4.w * vb1
                        + b5.x * ub2 + b5.y * vb2 + b5.z * ub3 + b5.w * vb3;
        const float exy = 0.5f * gxy;
        const float tr = exx + eyy, tr3 = tr * (1.f / 3.f);
        const float dxx = exx - tr3, dyy = eyy - tr3, dzz = -tr3;
        const float dev2 = dxx * dxx + dyy * dyy + dzz * dzz + 2.f * exy * exy;
        const float trp = fmaxf(tr, 0.f), trn = fminf(tr, 0.f);
        Eel += ((0.5f * K_MOD * trp * trp + MU_ * dev2) * g
                + 0.5f * K_MOD * trn * trn) * vipb;
    }

    Eel  = waveReduce(Eel);
    Efr  = waveReduce(Efr);
    Eirr = waveReduce(Eirr);
    __shared__ float sE[4], sF[4], sI[4];
    const int lane = threadIdx.x & 63, wid = threadIdx.x >> 6;
    if (lane == 0) { sE[wid] = Eel; sF[wid] = Efr; sI[wid] = Eirr; }
    __syncthreads();
    if (threadIdx.x == 0) {
        atomicAdd(&out[0], sE[0] + sE[1] + sE[2] + sE[3]);
        atomicAdd(&out[1], sF[0] + sF[1] + sF[2] + sF[3]);
        atomicAdd(&out[2], sI[0] + sI[1] + sI[2] + sI[3]);
    }
}

extern "C" void kernel_launch(void* const* d_in, const int* in_sizes, int n_in,
                              void* d_out, int out_size, void* d_ws, size_t ws_size,
                              hipStream_t stream) {
    const float* u      = (const float*)d_in[0];
    const float* v      = (const float*)d_in[1];
    const float* c      = (const float*)d_in[2];
    const float* prev_c = (const float*)d_in[3];
    const int*   conn   = (const int*)d_in[4];
    const float* Nf     = (const float*)d_in[5];
    const float* dNdx   = (const float*)d_in[6];
    const float* B      = (const float*)d_in[7];
    const float* vol    = (const float*)d_in[8];
    float* out = (float*)d_out;

    hipMemsetAsync(out, 0, 3 * sizeof(float), stream);

    if (ws_size >= WS_NEEDED) {
        float* ws = (float*)d_ws;
        gather_pack<<<(N_NODES + BLK - 1) / BLK, BLK, 0, stream>>>(
            u, v, c, prev_c, conn, ws, out);
        stream_energy<<<N_WORK / BLK, BLK, 0, stream>>>(
            ws, Nf, dNdx, B, vol, out);
    } else {
        fused_energy<<<(N_WORK / 2) / BLK, BLK, 0, stream>>>(
            u, v, c, prev_c, conn, Nf, dNdx, B, vol, out);
    }
}

// Round 6
// 50.912 us; speedup vs baseline: 2.7993x; 2.7993x over previous
//
#include <hip/hip_runtime.h>

namespace {
constexpr int N_ELEMS  = 262144;
constexpr int N_NODES  = 263169;
constexpr int N_WORK   = N_ELEMS * 4;     // 1048576 (element, ip) units
constexpr int NTHREADS = N_WORK / 2;      // 524288 — each thread does 2 units
constexpr int BLK      = 256;
constexpr int NBLOCKS  = NTHREADS / BLK;  // 2048 partial-sum slots

// folded material constants (fp32, match reference math)
constexpr float GC_2L0  = 0.09f;                 // G_C / (2*L_0)
constexpr float L0SQ    = 0.015f * 0.015f;
constexpr float MU_     = 80.76923076923077f;    // E/(2(1+nu))
constexpr float K_MOD   = 175.0f;                // lam + 2mu/3 (exact)
constexpr float PENALTY = 1799.82f;              // G_C/L_0*(1/PF_TOL^2-1)
}

typedef float vfloat4 __attribute__((ext_vector_type(4)));
typedef int   vint4   __attribute__((ext_vector_type(4)));

__device__ __forceinline__ float waveReduce(float x) {
#pragma unroll
    for (int off = 32; off; off >>= 1) x += __shfl_down(x, off, 64);
    return x;
}

__global__ __launch_bounds__(256) void fused_energy(
    const float* __restrict__ u, const float* __restrict__ v,
    const float* __restrict__ c, const float* __restrict__ prev_c,
    const int* __restrict__ conn,
    const float* __restrict__ Nf, const float* __restrict__ dNdx,
    const float* __restrict__ B, const float* __restrict__ vol,
    float* __restrict__ partials)
{
    const int tid = blockIdx.x * blockDim.x + threadIdx.x;
    const int u0 = tid, u1 = tid + NTHREADS;
    const int e0 = u0 >> 2, ip0 = u0 & 3;
    const int e1 = u1 >> 2, ip1 = u1 & 3;

    // ---- phase A: issue ALL independent loads up front ------------------
    const vint4 cn0 = *reinterpret_cast<const vint4*>(conn + 4ll * e0);
    const vint4 cn1 = *reinterpret_cast<const vint4*>(conn + 4ll * e1);

    const vfloat4 Nr0 = *reinterpret_cast<const vfloat4*>(Nf + 16ll * e0 + 4 * ip0);
    const vfloat4 Nr1 = *reinterpret_cast<const vfloat4*>(Nf + 16ll * e1 + 4 * ip1);

    const float* Dp0 = dNdx + 32ll * e0 + 8 * ip0;
    const float* Dp1 = dNdx + 32ll * e1 + 8 * ip1;
    const vfloat4 dxa = *reinterpret_cast<const vfloat4*>(Dp0);
    const vfloat4 dya = *reinterpret_cast<const vfloat4*>(Dp0 + 4);
    const vfloat4 dxb = *reinterpret_cast<const vfloat4*>(Dp1);
    const vfloat4 dyb = *reinterpret_cast<const vfloat4*>(Dp1 + 4);

    const float* Bp0 = B + 96ll * e0 + 24 * ip0;
    const float* Bp1 = B + 96ll * e1 + 24 * ip1;
    const vfloat4 a0 = *reinterpret_cast<const vfloat4*>(Bp0 +  0);
    const vfloat4 a1 = *reinterpret_cast<const vfloat4*>(Bp0 +  4);
    const vfloat4 a2 = *reinterpret_cast<const vfloat4*>(Bp0 +  8);
    const vfloat4 a3 = *reinterpret_cast<const vfloat4*>(Bp0 + 12);
    const vfloat4 a4 = *reinterpret_cast<const vfloat4*>(Bp0 + 16);
    const vfloat4 a5 = *reinterpret_cast<const vfloat4*>(Bp0 + 20);
    const vfloat4 b0 = *reinterpret_cast<const vfloat4*>(Bp1 +  0);
    const vfloat4 b1 = *reinterpret_cast<const vfloat4*>(Bp1 +  4);
    const vfloat4 b2 = *reinterpret_cast<const vfloat4*>(Bp1 +  8);
    const vfloat4 b3 = *reinterpret_cast<const vfloat4*>(Bp1 + 12);
    const vfloat4 b4 = *reinterpret_cast<const vfloat4*>(Bp1 + 16);
    const vfloat4 b5 = *reinterpret_cast<const vfloat4*>(Bp1 + 20);
    const float vipa = vol[4ll * e0 + ip0];
    const float vipb = vol[4ll * e1 + ip1];

    float Eirr = 0.f;
    if (tid < N_NODES) {
        float d = fmaxf(prev_c[tid] - c[tid], 0.f);
        Eirr = 0.5f * PENALTY * d * d;
    }

    // ---- gathers (depend only on cn0/cn1; all 24 batched) ---------------
    const float ca0 = c[cn0.x], ca1 = c[cn0.y], ca2 = c[cn0.z], ca3 = c[cn0.w];
    const float cb0 = c[cn1.x], cb1 = c[cn1.y], cb2 = c[cn1.z], cb3 = c[cn1.w];
    const float ua0 = u[cn0.x], va0 = v[cn0.x];
    const float ua1 = u[cn0.y], va1 = v[cn0.y];
    const float ua2 = u[cn0.z], va2 = v[cn0.z];
    const float ua3 = u[cn0.w], va3 = v[cn0.w];
    const float ub0 = u[cn1.x], vb0 = v[cn1.x];
    const float ub1 = u[cn1.y], vb1 = v[cn1.y];
    const float ub2 = u[cn1.z], vb2 = v[cn1.z];
    const float ub3 = u[cn1.w], vb3 = v[cn1.w];

    // ---- phase B: compute ------------------------------------------------
    float Eel = 0.f, Efr = 0.f;
    {   // unit 0
        const float o0 = 1.f - ca0, o1 = 1.f - ca1, o2 = 1.f - ca2, o3 = 1.f - ca3;
        const float omc = Nr0.x * o0 + Nr0.y * o1 + Nr0.z * o2 + Nr0.w * o3;
        const float g = omc * omc, cip = 1.f - omc;
        const float gx = dxa.x * ca0 + dxa.y * ca1 + dxa.z * ca2 + dxa.w * ca3;
        const float gy = dya.x * ca0 + dya.y * ca1 + dya.z * ca2 + dya.w * ca3;
        Efr += GC_2L0 * (cip * cip + L0SQ * (gx * gx + gy * gy)) * vipa;
        const float exx = a0.x * ua0 + a0.y * va0 + a0.z * ua1 + a0.w * va1
                        + a1.x * ua2 + a1.y * va2 + a1.z * ua3 + a1.w * va3;
        const float eyy = a2.x * ua0 + a2.y * va0 + a2.z * ua1 + a2.w * va1
                        + a3.x * ua2 + a3.y * va2 + a3.z * ua3 + a3.w * va3;
        const float gxy = a4.x * ua0 + a4.y * va0 + a4.z * ua1 + a4.w * va1
                        + a5.x * ua2 + a5.y * va2 + a5.z * ua3 + a5.w * va3;
        const float exy = 0.5f * gxy;
        const float tr = exx + eyy, tr3 = tr * (1.f / 3.f);
        const float dxx = exx - tr3, dyy = eyy - tr3, dzz = -tr3;
        const float dev2 = dxx * dxx + dyy * dyy + dzz * dzz + 2.f * exy * exy;
        const float trp = fmaxf(tr, 0.f), trn = fminf(tr, 0.f);
        Eel += ((0.5f * K_MOD * trp * trp + MU_ * dev2) * g
                + 0.5f * K_MOD * trn * trn) * vipa;
    }
    {   // unit 1
        const float o0 = 1.f - cb0, o1 = 1.f - cb1, o2 = 1.f - cb2, o3 = 1.f - cb3;
        const float omc = Nr1.x * o0 + Nr1.y * o1 + Nr1.z * o2 + Nr1.w * o3;
        const float g = omc * omc, cip = 1.f - omc;
        const float gx = dxb.x * cb0 + dxb.y * cb1 + dxb.z * cb2 + dxb.w * cb3;
        const float gy = dyb.x * cb0 + dyb.y * cb1 + dyb.z * cb2 + dyb.w * cb3;
        Efr += GC_2L0 * (cip * cip + L0SQ * (gx * gx + gy * gy)) * vipb;
        const float exx = b0.x * ub0 + b0.y * vb0 + b0.z * ub1 + b0.w * vb1
                        + b1.x * ub2 + b1.y * vb2 + b1.z * ub3 + b1.w * vb3;
        const float eyy = b2.x * ub0 + b2.y * vb0 + b2.z * ub1 + b2.w * vb1
                        + b3.x * ub2 + b3.y * vb2 + b3.z * ub3 + b3.w * vb3;
        const float gxy = b4.x * ub0 + b4.y * vb0 + b4.z * ub1 + b4.w * vb1
                        + b5.x * ub2 + b5.y * vb2 + b5.z * ub3 + b5.w * vb3;
        const float exy = 0.5f * gxy;
        const float tr = exx + eyy, tr3 = tr * (1.f / 3.f);
        const float dxx = exx - tr3, dyy = eyy - tr3, dzz = -tr3;
        const float dev2 = dxx * dxx + dyy * dyy + dzz * dzz + 2.f * exy * exy;
        const float trp = fmaxf(tr, 0.f), trn = fminf(tr, 0.f);
        Eel += ((0.5f * K_MOD * trp * trp + MU_ * dev2) * g
                + 0.5f * K_MOD * trn * trn) * vipb;
    }

    // ---- block reduction → contention-free partial store -----------------
    Eel  = waveReduce(Eel);
    Efr  = waveReduce(Efr);
    Eirr = waveReduce(Eirr);
    __shared__ float sE[4], sF[4], sI[4];
    const int lane = threadIdx.x & 63, wid = threadIdx.x >> 6;
    if (lane == 0) { sE[wid] = Eel; sF[wid] = Efr; sI[wid] = Eirr; }
    __syncthreads();
    if (threadIdx.x == 0) {
        float* p = partials + 3ll * blockIdx.x;
        p[0] = sE[0] + sE[1] + sE[2] + sE[3];
        p[1] = sF[0] + sF[1] + sF[2] + sF[3];
        p[2] = sI[0] + sI[1] + sI[2] + sI[3];
    }
}

__global__ __launch_bounds__(256) void final_reduce(
    const float* __restrict__ partials, float* __restrict__ out)
{
    float s0 = 0.f, s1 = 0.f, s2 = 0.f;
    for (int i = threadIdx.x; i < NBLOCKS; i += 256) {
        const float* p = partials + 3ll * i;
        s0 += p[0]; s1 += p[1]; s2 += p[2];
    }
    s0 = waveReduce(s0);
    s1 = waveReduce(s1);
    s2 = waveReduce(s2);
    __shared__ float sA[4], sB[4], sC[4];
    const int lane = threadIdx.x & 63, wid = threadIdx.x >> 6;
    if (lane == 0) { sA[wid] = s0; sB[wid] = s1; sC[wid] = s2; }
    __syncthreads();
    if (threadIdx.x == 0) {
        out[0] = sA[0] + sA[1] + sA[2] + sA[3];
        out[1] = sB[0] + sB[1] + sB[2] + sB[3];
        out[2] = sC[0] + sC[1] + sC[2] + sC[3];
    }
}

extern "C" void kernel_launch(void* const* d_in, const int* in_sizes, int n_in,
                              void* d_out, int out_size, void* d_ws, size_t ws_size,
                              hipStream_t stream) {
    const float* u      = (const float*)d_in[0];
    const float* v      = (const float*)d_in[1];
    const float* c      = (const float*)d_in[2];
    const float* prev_c = (const float*)d_in[3];
    const int*   conn   = (const int*)d_in[4];
    const float* Nf     = (const float*)d_in[5];
    const float* dNdx   = (const float*)d_in[6];
    const float* B      = (const float*)d_in[7];
    const float* vol    = (const float*)d_in[8];
    float* out      = (float*)d_out;
    float* partials = (float*)d_ws;   // 2048 * 3 floats = 24 KB

    fused_energy<<<NBLOCKS, BLK, 0, stream>>>(
        u, v, c, prev_c, conn, Nf, dNdx, B, vol, partials);
    final_reduce<<<1, BLK, 0, stream>>>(partials, out);
}

// Round 7
// 48.119 us; speedup vs baseline: 2.9618x; 1.0581x over previous
//
#include <hip/hip_runtime.h>

namespace {
constexpr int N_ELEMS  = 262144;
constexpr int N_NODES  = 263169;
constexpr int NTHREADS = N_ELEMS * 2;     // thread t -> element t/2, ip pair (t&1, (t&1)+2)
constexpr int BLK      = 256;
constexpr int NBLOCKS  = NTHREADS / BLK;  // 2048 partial-sum slots

// folded material constants (fp32, match reference math)
constexpr float GC_2L0  = 0.09f;                 // G_C / (2*L_0)
constexpr float L0SQ    = 0.015f * 0.015f;
constexpr float MU_     = 80.76923076923077f;    // E/(2(1+nu))
constexpr float K_MOD   = 175.0f;                // lam + 2mu/3 (exact)
constexpr float PENALTY = 1799.82f;              // G_C/L_0*(1/PF_TOL^2-1)
}

typedef float vfloat4 __attribute__((ext_vector_type(4)));
typedef int   vint4   __attribute__((ext_vector_type(4)));

__device__ __forceinline__ float waveReduce(float x) {
#pragma unroll
    for (int off = 32; off; off >>= 1) x += __shfl_down(x, off, 64);
    return x;
}

__global__ __launch_bounds__(256) void fused_energy(
    const float* __restrict__ u, const float* __restrict__ v,
    const float* __restrict__ c, const float* __restrict__ prev_c,
    const int* __restrict__ conn,
    const float* __restrict__ Nf, const float* __restrict__ dNdx,
    const float* __restrict__ B, const float* __restrict__ vol,
    float* __restrict__ partials)
{
    const int t = blockIdx.x * blockDim.x + threadIdx.x;   // 0..NTHREADS-1
    const int e    = t >> 1;
    const int iplo = t & 1;            // this thread: ip = iplo and iplo+2
    const bool ev  = (iplo == 0);      // lane parity == t parity (BLK % 64 == 0)

    // ---- dense loads (all independent, issued up front) ------------------
    const vint4 cn = *reinterpret_cast<const vint4*>(conn + 4ll * e);

    const vfloat4 NrA = *reinterpret_cast<const vfloat4*>(Nf + 16ll * e + 4 * iplo);
    const vfloat4 NrB = *reinterpret_cast<const vfloat4*>(Nf + 16ll * e + 4 * iplo + 8);

    const float* Dp = dNdx + 32ll * e + 8 * iplo;
    const vfloat4 dxA = *reinterpret_cast<const vfloat4*>(Dp);
    const vfloat4 dyA = *reinterpret_cast<const vfloat4*>(Dp + 4);
    const vfloat4 dxB = *reinterpret_cast<const vfloat4*>(Dp + 16);
    const vfloat4 dyB = *reinterpret_cast<const vfloat4*>(Dp + 20);

    const float* Bp = B + 96ll * e + 24 * iplo;
    const vfloat4 a0 = *reinterpret_cast<const vfloat4*>(Bp +  0);
    const vfloat4 a1 = *reinterpret_cast<const vfloat4*>(Bp +  4);
    const vfloat4 a2 = *reinterpret_cast<const vfloat4*>(Bp +  8);
    const vfloat4 a3 = *reinterpret_cast<const vfloat4*>(Bp + 12);
    const vfloat4 a4 = *reinterpret_cast<const vfloat4*>(Bp + 16);
    const vfloat4 a5 = *reinterpret_cast<const vfloat4*>(Bp + 20);
    const vfloat4 q0 = *reinterpret_cast<const vfloat4*>(Bp + 48);
    const vfloat4 q1 = *reinterpret_cast<const vfloat4*>(Bp + 52);
    const vfloat4 q2 = *reinterpret_cast<const vfloat4*>(Bp + 56);
    const vfloat4 q3 = *reinterpret_cast<const vfloat4*>(Bp + 60);
    const vfloat4 q4 = *reinterpret_cast<const vfloat4*>(Bp + 64);
    const vfloat4 q5 = *reinterpret_cast<const vfloat4*>(Bp + 68);

    const float vipA = vol[4ll * e + iplo];
    const float vipB = vol[4ll * e + iplo + 2];

    float Eirr = 0.f;
    if (t < N_NODES) {
        float d = fmaxf(prev_c[t] - c[t], 0.f);
        Eirr = 0.5f * PENALTY * d * d;
    }

    // ---- split gathers: even lane takes {c0..c3,u0,u1}, odd {v0..v3,u2,u3}
    const float* A  = ev ? c : v;
    const int  idx4 = ev ? cn.x : cn.z;
    const int  idx5 = ev ? cn.y : cn.w;
    const float g0 = A[cn.x], g1 = A[cn.y], g2 = A[cn.z], g3 = A[cn.w];
    const float g4 = u[idx4], g5 = u[idx5];

    const float p0 = __shfl_xor(g0, 1);
    const float p1 = __shfl_xor(g1, 1);
    const float p2 = __shfl_xor(g2, 1);
    const float p3 = __shfl_xor(g3, 1);
    const float p4 = __shfl_xor(g4, 1);
    const float p5 = __shfl_xor(g5, 1);

    const float c0 = ev ? g0 : p0, c1 = ev ? g1 : p1;
    const float c2 = ev ? g2 : p2, c3 = ev ? g3 : p3;
    const float v0 = ev ? p0 : g0, v1 = ev ? p1 : g1;
    const float v2 = ev ? p2 : g2, v3 = ev ? p3 : g3;
    const float u0 = ev ? g4 : p4, u1 = ev ? g5 : p5;
    const float u2 = ev ? p4 : g4, u3 = ev ? p5 : g5;

    // ---- compute ---------------------------------------------------------
    const float o0 = 1.f - c0, o1 = 1.f - c1, o2 = 1.f - c2, o3 = 1.f - c3;

    float Eel = 0.f, Efr = 0.f;
    {   // unit A: ip = iplo
        const float omc = NrA.x * o0 + NrA.y * o1 + NrA.z * o2 + NrA.w * o3;
        const float g = omc * omc, cip = 1.f - omc;
        const float gx = dxA.x * c0 + dxA.y * c1 + dxA.z * c2 + dxA.w * c3;
        const float gy = dyA.x * c0 + dyA.y * c1 + dyA.z * c2 + dyA.w * c3;
        Efr += GC_2L0 * (cip * cip + L0SQ * (gx * gx + gy * gy)) * vipA;

        const float exx = a0.x * u0 + a0.y * v0 + a0.z * u1 + a0.w * v1
                        + a1.x * u2 + a1.y * v2 + a1.z * u3 + a1.w * v3;
        const float eyy = a2.x * u0 + a2.y * v0 + a2.z * u1 + a2.w * v1
                        + a3.x * u2 + a3.y * v2 + a3.z * u3 + a3.w * v3;
        const float gxy = a4.x * u0 + a4.y * v0 + a4.z * u1 + a4.w * v1
                        + a5.x * u2 + a5.y * v2 + a5.z * u3 + a5.w * v3;
        const float exy = 0.5f * gxy;
        const float tr = exx + eyy, tr3 = tr * (1.f / 3.f);
        const float dxx = exx - tr3, dyy = eyy - tr3, dzz = -tr3;
        const float dev2 = dxx * dxx + dyy * dyy + dzz * dzz + 2.f * exy * exy;
        const float trp = fmaxf(tr, 0.f), trn = fminf(tr, 0.f);
        Eel += ((0.5f * K_MOD * trp * trp + MU_ * dev2) * g
                + 0.5f * K_MOD * trn * trn) * vipA;
    }
    {   // unit B: ip = iplo + 2
        const float omc = NrB.x * o0 + NrB.y * o1 + NrB.z * o2 + NrB.w * o3;
        const float g = omc * omc, cip = 1.f - omc;
        const float gx = dxB.x * c0 + dxB.y * c1 + dxB.z * c2 + dxB.w * c3;
        const float gy = dyB.x * c0 + dyB.y * c1 + dyB.z * c2 + dyB.w * c3;
        Efr += GC_2L0 * (cip * cip + L0SQ * (gx * gx + gy * gy)) * vipB;

        const float exx = q0.x * u0 + q0.y * v0 + q0.z * u1 + q0.w * v1
                        + q1.x * u2 + q1.y * v2 + q1.z * u3 + q1.w * v3;
        const float eyy = q2.x * u0 + q2.y * v0 + q2.z * u1 + q2.w * v1
                        + q3.x * u2 + q3.y * v2 + q3.z * u3 + q3.w * v3;
        const float gxy = q4.x * u0 + q4.y * v0 + q4.z * u1 + q4.w * v1
                        + q5.x * u2 + q5.y * v2 + q5.z * u3 + q5.w * v3;
        const float exy = 0.5f * gxy;
        const float tr = exx + eyy, tr3 = tr * (1.f / 3.f);
        const float dxx = exx - tr3, dyy = eyy - tr3, dzz = -tr3;
        const float dev2 = dxx * dxx + dyy * dyy + dzz * dzz + 2.f * exy * exy;
        const float trp = fmaxf(tr, 0.f), trn = fminf(tr, 0.f);
        Eel += ((0.5f * K_MOD * trp * trp + MU_ * dev2) * g
                + 0.5f * K_MOD * trn * trn) * vipB;
    }

    // ---- block reduction → contention-free partial store -----------------
    Eel  = waveReduce(Eel);
    Efr  = waveReduce(Efr);
    Eirr = waveReduce(Eirr);
    __shared__ float sE[4], sF[4], sI[4];
    const int lane = threadIdx.x & 63, wid = threadIdx.x >> 6;
    if (lane == 0) { sE[wid] = Eel; sF[wid] = Efr; sI[wid] = Eirr; }
    __syncthreads();
    if (threadIdx.x == 0) {
        float* p = partials + 3ll * blockIdx.x;
        p[0] = sE[0] + sE[1] + sE[2] + sE[3];
        p[1] = sF[0] + sF[1] + sF[2] + sF[3];
        p[2] = sI[0] + sI[1] + sI[2] + sI[3];
    }
}

__global__ __launch_bounds__(256) void final_reduce(
    const float* __restrict__ partials, float* __restrict__ out)
{
    float s0 = 0.f, s1 = 0.f, s2 = 0.f;
    for (int i = threadIdx.x; i < NBLOCKS; i += 256) {
        const float* p = partials + 3ll * i;
        s0 += p[0]; s1 += p[1]; s2 += p[2];
    }
    s0 = waveReduce(s0);
    s1 = waveReduce(s1);
    s2 = waveReduce(s2);
    __shared__ float sA[4], sB[4], sC[4];
    const int lane = threadIdx.x & 63, wid = threadIdx.x >> 6;
    if (lane == 0) { sA[wid] = s0; sB[wid] = s1; sC[wid] = s2; }
    __syncthreads();
    if (threadIdx.x == 0) {
        out[0] = sA[0] + sA[1] + sA[2] + sA[3];
        out[1] = sB[0] + sB[1] + sB[2] + sB[3];
        out[2] = sC[0] + sC[1] + sC[2] + sC[3];
    }
}

extern "C" void kernel_launch(void* const* d_in, const int* in_sizes, int n_in,
                              void* d_out, int out_size, void* d_ws, size_t ws_size,
                              hipStream_t stream) {
    const float* u      = (const float*)d_in[0];
    const float* v      = (const float*)d_in[1];
    const float* c      = (const float*)d_in[2];
    const float* prev_c = (const float*)d_in[3];
    const int*   conn   = (const int*)d_in[4];
    const float* Nf     = (const float*)d_in[5];
    const float* dNdx   = (const float*)d_in[6];
    const float* B      = (const float*)d_in[7];
    const float* vol    = (const float*)d_in[8];
    float* out      = (float*)d_out;
    float* partials = (float*)d_ws;   // 2048 * 3 floats = 24 KB

    fused_energy<<<NBLOCKS, BLK, 0, stream>>>(
        u, v, c, prev_c, conn, Nf, dNdx, B, vol, partials);
    final_reduce<<<1, BLK, 0, stream>>>(partials, out);
}